// Round 1
// baseline (1297.958 us; speedup 1.0000x reference)
//
#include <hip/hip_runtime.h>

#define FIN 512
#define HID 256
#define CLS 64

__device__ __forceinline__ float bf2f(unsigned short u) {
    union { unsigned int i; float f; } c; c.i = ((unsigned int)u) << 16; return c.f;
}
__device__ __forceinline__ unsigned short f2bf(float f) {
    union { float f; unsigned int u; } c; c.f = f;
    unsigned int u = c.u;
    return (unsigned short)((u + 0x7fffu + ((u >> 16) & 1u)) >> 16);
}

// ---------------- CSR build ----------------
__global__ void k_deg(const int* __restrict__ dst, int* __restrict__ degi, int E) {
    int i = blockIdx.x * blockDim.x + threadIdx.x;
    if (i < E) atomicAdd(&degi[dst[i]], 1);
}

__global__ void k_bsum(const int* __restrict__ degi, int* __restrict__ bsum, int Nn) {
    __shared__ int sh[256];
    int i = blockIdx.x * 256 + threadIdx.x;
    sh[threadIdx.x] = (i < Nn) ? degi[i] : 0;
    __syncthreads();
    for (int s = 128; s > 0; s >>= 1) {
        if (threadIdx.x < s) sh[threadIdx.x] += sh[threadIdx.x + s];
        __syncthreads();
    }
    if (threadIdx.x == 0) bsum[blockIdx.x] = sh[0];
}

__global__ void k_scan(const int* __restrict__ degi, const int* __restrict__ bsum,
                       int* __restrict__ rs, int* __restrict__ cursor,
                       float* __restrict__ dinv, int Nn, int E) {
    __shared__ int sh[256];
    __shared__ int offs;
    int b = blockIdx.x, tid = threadIdx.x;
    int part = 0;
    for (int j = tid; j < b; j += 256) part += bsum[j];
    sh[tid] = part; __syncthreads();
    for (int s = 128; s > 0; s >>= 1) {
        if (tid < s) sh[tid] += sh[tid + s];
        __syncthreads();
    }
    if (tid == 0) offs = sh[0];
    __syncthreads();
    int off0 = offs;
    int i = b * 256 + tid;
    int dval = (i < Nn) ? degi[i] : 0;
    sh[tid] = dval; __syncthreads();
    for (int s = 1; s < 256; s <<= 1) {
        int t = (tid >= s) ? sh[tid - s] : 0;
        __syncthreads();
        sh[tid] += t;
        __syncthreads();
    }
    if (i < Nn) {
        int excl = off0 + sh[tid] - dval;
        rs[i] = excl;
        cursor[i] = excl;
        dinv[i] = rsqrtf((float)(dval + 1));   // +1 = self loop
    }
    if (b == 0 && tid == 0) rs[Nn] = E;
}

__global__ void k_scatter(const int* __restrict__ src, const int* __restrict__ dst,
                          int* __restrict__ cursor, int* __restrict__ csr, int E) {
    int i = blockIdx.x * blockDim.x + threadIdx.x;
    if (i < E) {
        int d = dst[i];
        int p = atomicAdd(&cursor[d], 1);
        csr[p] = src[i];
    }
}

// ---------------- GEMM1: hs1 = (x @ W1 + b1) * dinv[row], fp32 -> bf16 ----------------
#define BM 64
#define BN 64
#define BK 32

__global__ __launch_bounds__(256) void k_gemm1(
        const float* __restrict__ x, const float* __restrict__ W1,
        const float* __restrict__ b1, const float* __restrict__ dinv,
        unsigned short* __restrict__ hs1, int Nn) {
    __shared__ float As[BK][BM + 4];   // [k][m]
    __shared__ float Bs[BK][BN + 4];   // [k][n]
    int bm = blockIdx.x, bn = blockIdx.y;
    int tid = threadIdx.x;
    int tx = tid & 15, ty = tid >> 4;
    int row0 = bm * BM, col0 = bn * BN;
    float acc[4][4] = {};
    for (int kt = 0; kt < FIN; kt += BK) {
        #pragma unroll
        for (int it = 0; it < 2; ++it) {
            int idx = tid + it * 256;       // 0..511
            int r = idx >> 3, c4 = idx & 7; // 64 rows x 8 float4
            int gm = row0 + r;
            float4 v = make_float4(0.f, 0.f, 0.f, 0.f);
            if (gm < Nn) v = *(const float4*)&x[(size_t)gm * FIN + kt + c4 * 4];
            As[c4 * 4 + 0][r] = v.x;
            As[c4 * 4 + 1][r] = v.y;
            As[c4 * 4 + 2][r] = v.z;
            As[c4 * 4 + 3][r] = v.w;
        }
        #pragma unroll
        for (int it = 0; it < 2; ++it) {
            int idx = tid + it * 256;
            int r = idx >> 4, c4 = idx & 15; // 32 rows x 16 float4
            *(float4*)&Bs[r][c4 * 4] =
                *(const float4*)&W1[(size_t)(kt + r) * HID + col0 + c4 * 4];
        }
        __syncthreads();
        #pragma unroll
        for (int k = 0; k < BK; ++k) {
            float4 a = *(const float4*)&As[k][ty * 4];
            float4 b = *(const float4*)&Bs[k][tx * 4];
            float av[4] = {a.x, a.y, a.z, a.w};
            float bv[4] = {b.x, b.y, b.z, b.w};
            #pragma unroll
            for (int i = 0; i < 4; ++i)
                #pragma unroll
                for (int j = 0; j < 4; ++j)
                    acc[i][j] += av[i] * bv[j];
        }
        __syncthreads();
    }
    #pragma unroll
    for (int i = 0; i < 4; ++i) {
        int m = row0 + ty * 4 + i;
        if (m >= Nn) continue;
        float dv = dinv[m];
        #pragma unroll
        for (int j = 0; j < 4; ++j) {
            int n = col0 + tx * 4 + j;
            hs1[(size_t)m * HID + n] = f2bf((acc[i][j] + b1[n]) * dv);
        }
    }
}

// ---------------- Agg1: h2in[d] = relu(dinv[d] * (sum hs1[s] + hs1[d])) ----------------
__global__ __launch_bounds__(64) void k_agg1(
        const unsigned short* __restrict__ hs1, const int* __restrict__ csr,
        const int* __restrict__ rs, const float* __restrict__ dinv,
        unsigned short* __restrict__ h2in) {
    int d = blockIdx.x;
    int lane = threadIdx.x;
    size_t selfoff = (size_t)d * HID + lane * 4;
    ushort4 sv = *(const ushort4*)&hs1[selfoff];
    float a0 = bf2f(sv.x), a1 = bf2f(sv.y), a2 = bf2f(sv.z), a3 = bf2f(sv.w);
    int j1 = rs[d + 1];
    for (int j = rs[d]; j < j1; ++j) {
        int s = csr[j];
        ushort4 v = *(const ushort4*)&hs1[(size_t)s * HID + lane * 4];
        a0 += bf2f(v.x); a1 += bf2f(v.y); a2 += bf2f(v.z); a3 += bf2f(v.w);
    }
    float dv = dinv[d];
    ushort4 o;
    o.x = f2bf(fmaxf(a0 * dv, 0.f));
    o.y = f2bf(fmaxf(a1 * dv, 0.f));
    o.z = f2bf(fmaxf(a2 * dv, 0.f));
    o.w = f2bf(fmaxf(a3 * dv, 0.f));
    *(ushort4*)&h2in[selfoff] = o;
}

// ---------------- W2 -> bf16 ----------------
__global__ void k_w2cvt(const float* __restrict__ W2, unsigned short* __restrict__ w2b, int n) {
    int i = blockIdx.x * blockDim.x + threadIdx.x;
    if (i < n) w2b[i] = f2bf(W2[i]);
}

// ---------------- GEMM2 (wave-per-row matvec): hs2 = (h2in @ W2 + b2) * dinv ----------------
__global__ __launch_bounds__(64) void k_gemm2(
        const unsigned short* __restrict__ h2in, const unsigned short* __restrict__ w2b,
        const float* __restrict__ b2, const float* __restrict__ dinv,
        unsigned short* __restrict__ hs2) {
    __shared__ float hrow[HID];
    int d = blockIdx.x, lane = threadIdx.x;
    ushort4 v = *(const ushort4*)&h2in[(size_t)d * HID + lane * 4];
    hrow[lane * 4 + 0] = bf2f(v.x);
    hrow[lane * 4 + 1] = bf2f(v.y);
    hrow[lane * 4 + 2] = bf2f(v.z);
    hrow[lane * 4 + 3] = bf2f(v.w);
    __syncthreads();
    float acc = b2[lane];
    #pragma unroll 8
    for (int k = 0; k < HID; ++k)
        acc += hrow[k] * bf2f(w2b[k * CLS + lane]);
    hs2[(size_t)d * CLS + lane] = f2bf(acc * dinv[d]);
}

// ---------------- Agg2 + log_softmax ----------------
__global__ __launch_bounds__(64) void k_agg2(
        const unsigned short* __restrict__ hs2, const int* __restrict__ csr,
        const int* __restrict__ rs, const float* __restrict__ dinv,
        float* __restrict__ out) {
    int d = blockIdx.x, lane = threadIdx.x;
    float acc = bf2f(hs2[(size_t)d * CLS + lane]);  // self
    int j1 = rs[d + 1];
    for (int j = rs[d]; j < j1; ++j) {
        int s = csr[j];
        acc += bf2f(hs2[(size_t)s * CLS + lane]);
    }
    float y = acc * dinv[d];
    float m = y;
    #pragma unroll
    for (int o = 32; o >= 1; o >>= 1) m = fmaxf(m, __shfl_xor(m, o, 64));
    float e = __expf(y - m);
    float ssum = e;
    #pragma unroll
    for (int o = 32; o >= 1; o >>= 1) ssum += __shfl_xor(ssum, o, 64);
    out[(size_t)d * CLS + lane] = y - m - __logf(ssum);
}

extern "C" void kernel_launch(void* const* d_in, const int* in_sizes, int n_in,
                              void* d_out, int out_size, void* d_ws, size_t ws_size,
                              hipStream_t stream) {
    const float* x  = (const float*)d_in[0];
    const int* ei   = (const int*)d_in[1];
    const float* W1 = (const float*)d_in[2];
    const float* b1 = (const float*)d_in[3];
    const float* W2 = (const float*)d_in[4];
    const float* b2 = (const float*)d_in[5];
    float* out = (float*)d_out;

    const int N = in_sizes[0] / FIN;
    const int E = in_sizes[1] / 2;
    const int* srcp = ei;
    const int* dstp = ei + E;

    // workspace carve-out
    char* w = (char*)d_ws;
    auto alloc = [&](size_t bytes) -> void* {
        void* p = (void*)w;
        w += (bytes + 255) / 256 * 256;
        return p;
    };
    int* degi   = (int*)alloc((size_t)N * 4);
    int* rs     = (int*)alloc((size_t)(N + 1) * 4);
    int* cursor = (int*)alloc((size_t)N * 4);
    int* bsum   = (int*)alloc(1024 * 4);
    float* dinv = (float*)alloc((size_t)N * 4);
    int* csr    = (int*)alloc((size_t)E * 4);
    unsigned short* hs1  = (unsigned short*)alloc((size_t)N * HID * 2);
    unsigned short* h2in = (unsigned short*)alloc((size_t)N * HID * 2);
    unsigned short* hs2  = (unsigned short*)alloc((size_t)N * CLS * 2);
    unsigned short* w2b  = (unsigned short*)alloc((size_t)HID * CLS * 2);

    const int nbE = (E + 255) / 256;
    const int nbN = (N + 255) / 256;

    hipMemsetAsync(degi, 0, (size_t)N * 4, stream);
    k_deg<<<nbE, 256, 0, stream>>>(dstp, degi, E);
    k_bsum<<<nbN, 256, 0, stream>>>(degi, bsum, N);
    k_scan<<<nbN, 256, 0, stream>>>(degi, bsum, rs, cursor, dinv, N, E);
    k_scatter<<<nbE, 256, 0, stream>>>(srcp, dstp, cursor, csr, E);
    k_w2cvt<<<(HID * CLS + 255) / 256, 256, 0, stream>>>(W2, w2b, HID * CLS);

    dim3 g1((N + BM - 1) / BM, HID / BN);
    k_gemm1<<<g1, 256, 0, stream>>>(x, W1, b1, dinv, hs1, N);
    k_agg1<<<N, 64, 0, stream>>>(hs1, csr, rs, dinv, h2in);
    k_gemm2<<<N, 64, 0, stream>>>(h2in, w2b, b2, dinv, hs2);
    k_agg2<<<N, 64, 0, stream>>>(hs2, csr, rs, dinv, out);
}

// Round 2
// 790.386 us; speedup vs baseline: 1.6422x; 1.6422x over previous
//
#include <hip/hip_runtime.h>

#define FIN 512
#define HID 256
#define CLS 64

typedef short bf16x8 __attribute__((ext_vector_type(8)));
typedef float f32x4 __attribute__((ext_vector_type(4)));

__device__ __forceinline__ float bf2f(unsigned short u) {
    union { unsigned int i; float f; } c; c.i = ((unsigned int)u) << 16; return c.f;
}
__device__ __forceinline__ unsigned short f2bf(float f) {
    union { float f; unsigned int u; } c; c.f = f;
    unsigned int u = c.u;
    return (unsigned short)((u + 0x7fffu + ((u >> 16) & 1u)) >> 16);
}

// ---------------- CSR build ----------------
__global__ void k_deg(const int* __restrict__ dst, int* __restrict__ degi, int E) {
    int i = blockIdx.x * blockDim.x + threadIdx.x;
    if (i < E) atomicAdd(&degi[dst[i]], 1);
}

__global__ void k_bsum(const int* __restrict__ degi, int* __restrict__ bsum, int Nn) {
    __shared__ int sh[256];
    int i = blockIdx.x * 256 + threadIdx.x;
    sh[threadIdx.x] = (i < Nn) ? degi[i] : 0;
    __syncthreads();
    for (int s = 128; s > 0; s >>= 1) {
        if (threadIdx.x < s) sh[threadIdx.x] += sh[threadIdx.x + s];
        __syncthreads();
    }
    if (threadIdx.x == 0) bsum[blockIdx.x] = sh[0];
}

__global__ void k_scan(const int* __restrict__ degi, const int* __restrict__ bsum,
                       int* __restrict__ rs, int* __restrict__ cursor,
                       float* __restrict__ dinv, int Nn, int E) {
    __shared__ int sh[256];
    __shared__ int offs;
    int b = blockIdx.x, tid = threadIdx.x;
    int part = 0;
    for (int j = tid; j < b; j += 256) part += bsum[j];
    sh[tid] = part; __syncthreads();
    for (int s = 128; s > 0; s >>= 1) {
        if (tid < s) sh[tid] += sh[tid + s];
        __syncthreads();
    }
    if (tid == 0) offs = sh[0];
    __syncthreads();
    int off0 = offs;
    int i = b * 256 + tid;
    int dval = (i < Nn) ? degi[i] : 0;
    sh[tid] = dval; __syncthreads();
    for (int s = 1; s < 256; s <<= 1) {
        int t = (tid >= s) ? sh[tid - s] : 0;
        __syncthreads();
        sh[tid] += t;
        __syncthreads();
    }
    if (i < Nn) {
        int excl = off0 + sh[tid] - dval;
        rs[i] = excl;
        cursor[i] = excl;
        dinv[i] = rsqrtf((float)(dval + 1));   // +1 = self loop
    }
    if (b == 0 && tid == 0) rs[Nn] = E;
}

__global__ void k_scatter(const int* __restrict__ src, const int* __restrict__ dst,
                          int* __restrict__ cursor, int* __restrict__ csr, int E) {
    int i = blockIdx.x * blockDim.x + threadIdx.x;
    if (i < E) {
        int d = dst[i];
        int p = atomicAdd(&cursor[d], 1);
        csr[p] = src[i];
    }
}

// ---------------- Weight pack: (k,n) -> Wp[((k>>3)*Ncols + n)*8 + (k&7)] ----------------
__global__ void k_wpack(const float* __restrict__ W, unsigned short* __restrict__ Wp,
                        int K, int Ncols) {
    int i = blockIdx.x * blockDim.x + threadIdx.x;
    if (i < K * Ncols) {
        int k = i / Ncols, n = i - k * Ncols;
        Wp[((size_t)(k >> 3) * Ncols + n) * 8 + (k & 7)] = f2bf(W[i]);
    }
}

// ---------------- GEMM1 (MFMA bf16): hs1 = (x @ W1 + b1) * dinv[row] ----------------
// 512 threads = 8 waves (2 row-waves x 4 col-waves). BM=64, BN=256 (full HID).
__global__ __launch_bounds__(512) void k_gemm1(
        const float* __restrict__ x, const unsigned short* __restrict__ W1p,
        const float* __restrict__ b1, const float* __restrict__ dinv,
        unsigned short* __restrict__ hs1, int Nn) {
    __shared__ unsigned short As[64][40];   // 32 k + 8 pad -> conflict-free b128 reads
    int tid = threadIdx.x;
    int w = tid >> 6, lane = tid & 63;
    int wr = w >> 2, wc = w & 3;
    int l15 = lane & 15, l4 = lane >> 4;
    int row0 = blockIdx.x * 64;

    f32x4 zero = {0.f, 0.f, 0.f, 0.f};
    f32x4 acc[2][4];
    #pragma unroll
    for (int m = 0; m < 2; ++m)
        #pragma unroll
        for (int n = 0; n < 4; ++n) acc[m][n] = zero;

    int sr = tid >> 3;          // 0..63 staging row
    int sc = tid & 7;           // 0..7  staging float4 col
    bool srok = (row0 + sr) < Nn;
    const float* xrow = x + (size_t)(row0 + sr) * FIN + sc * 4;

    for (int kt = 0; kt < FIN; kt += 32) {
        float4 v = srok ? *(const float4*)(xrow + kt) : make_float4(0.f, 0.f, 0.f, 0.f);
        ushort4 o;
        o.x = f2bf(v.x); o.y = f2bf(v.y); o.z = f2bf(v.z); o.w = f2bf(v.w);
        *(ushort4*)&As[sr][sc * 4] = o;
        __syncthreads();

        bf16x8 bfr[4];
        size_t bbase = (size_t)((kt >> 3) + l4) * HID * 8;
        #pragma unroll
        for (int n = 0; n < 4; ++n) {
            int col = wc * 64 + n * 16 + l15;
            bfr[n] = *(const bf16x8*)&W1p[bbase + (size_t)col * 8];
        }
        bf16x8 afr[2];
        #pragma unroll
        for (int m = 0; m < 2; ++m) {
            int r = wr * 32 + m * 16 + l15;
            afr[m] = *(const bf16x8*)&As[r][l4 * 8];
        }
        #pragma unroll
        for (int m = 0; m < 2; ++m)
            #pragma unroll
            for (int n = 0; n < 4; ++n)
                acc[m][n] = __builtin_amdgcn_mfma_f32_16x16x32_bf16(
                    afr[m], bfr[n], acc[m][n], 0, 0, 0);
        __syncthreads();
    }

    float b1c[4];
    #pragma unroll
    for (int n = 0; n < 4; ++n) b1c[n] = b1[wc * 64 + n * 16 + l15];
    #pragma unroll
    for (int m = 0; m < 2; ++m) {
        #pragma unroll
        for (int r = 0; r < 4; ++r) {
            int row = row0 + wr * 32 + m * 16 + l4 * 4 + r;
            if (row < Nn) {
                float dv = dinv[row];
                #pragma unroll
                for (int n = 0; n < 4; ++n) {
                    int col = wc * 64 + n * 16 + l15;
                    hs1[(size_t)row * HID + col] = f2bf((acc[m][n][r] + b1c[n]) * dv);
                }
            }
        }
    }
}

// ---------------- Agg1: h2in[d] = relu(dinv[d]*(sum_s hs1[s] + hs1[d])), 4 waves/dst ----------------
__global__ __launch_bounds__(256) void k_agg1(
        const unsigned short* __restrict__ hs1, const int* __restrict__ csr,
        const int* __restrict__ rs, const float* __restrict__ dinv,
        unsigned short* __restrict__ h2in) {
    __shared__ float sh[4][256];
    int d = blockIdx.x;
    int tid = threadIdx.x;
    int q = tid >> 6, lane = tid & 63;
    int base = rs[d], cnt = rs[d + 1] - base;
    float a0 = 0.f, a1 = 0.f, a2 = 0.f, a3 = 0.f;
    if (q == 0) {  // self loop
        ushort4 v = *(const ushort4*)&hs1[(size_t)d * HID + lane * 4];
        a0 = bf2f(v.x); a1 = bf2f(v.y); a2 = bf2f(v.z); a3 = bf2f(v.w);
    }
    int t = q;
    for (; t + 4 < cnt; t += 8) {
        int s0 = csr[base + t];
        int s1 = csr[base + t + 4];
        ushort4 v0 = *(const ushort4*)&hs1[(size_t)s0 * HID + lane * 4];
        ushort4 v1 = *(const ushort4*)&hs1[(size_t)s1 * HID + lane * 4];
        a0 += bf2f(v0.x) + bf2f(v1.x);
        a1 += bf2f(v0.y) + bf2f(v1.y);
        a2 += bf2f(v0.z) + bf2f(v1.z);
        a3 += bf2f(v0.w) + bf2f(v1.w);
    }
    if (t < cnt) {
        int s0 = csr[base + t];
        ushort4 v0 = *(const ushort4*)&hs1[(size_t)s0 * HID + lane * 4];
        a0 += bf2f(v0.x); a1 += bf2f(v0.y); a2 += bf2f(v0.z); a3 += bf2f(v0.w);
    }
    f32x4 p = {a0, a1, a2, a3};
    *(f32x4*)&sh[q][lane * 4] = p;
    __syncthreads();
    if (tid < 64) {
        f32x4 s0 = *(const f32x4*)&sh[0][tid * 4];
        f32x4 s1 = *(const f32x4*)&sh[1][tid * 4];
        f32x4 s2 = *(const f32x4*)&sh[2][tid * 4];
        f32x4 s3 = *(const f32x4*)&sh[3][tid * 4];
        float dv = dinv[d];
        ushort4 o;
        o.x = f2bf(fmaxf((s0[0] + s1[0] + s2[0] + s3[0]) * dv, 0.f));
        o.y = f2bf(fmaxf((s0[1] + s1[1] + s2[1] + s3[1]) * dv, 0.f));
        o.z = f2bf(fmaxf((s0[2] + s1[2] + s2[2] + s3[2]) * dv, 0.f));
        o.w = f2bf(fmaxf((s0[3] + s1[3] + s2[3] + s3[3]) * dv, 0.f));
        *(ushort4*)&h2in[(size_t)d * HID + tid * 4] = o;
    }
}

// ---------------- GEMM2 (MFMA): hs2 = (h2in @ W2 + b2) * dinv, no LDS ----------------
__global__ __launch_bounds__(256) void k_gemm2(
        const unsigned short* __restrict__ h2in, const unsigned short* __restrict__ W2p,
        const float* __restrict__ b2, const float* __restrict__ dinv,
        unsigned short* __restrict__ hs2, int Nn) {
    int tid = threadIdx.x;
    int w = tid >> 6, lane = tid & 63;
    int l15 = lane & 15, l4 = lane >> 4;
    int r0 = blockIdx.x * 64 + w * 16;
    int arow = r0 + l15;
    bool aok = arow < Nn;
    const unsigned short* ap = h2in + (size_t)arow * HID + l4 * 8;

    f32x4 zero = {0.f, 0.f, 0.f, 0.f};
    bf16x8 zf = {0, 0, 0, 0, 0, 0, 0, 0};
    f32x4 acc[4];
    #pragma unroll
    for (int n = 0; n < 4; ++n) acc[n] = zero;

    #pragma unroll
    for (int kt = 0; kt < HID; kt += 32) {
        bf16x8 a = aok ? *(const bf16x8*)(ap + kt) : zf;
        size_t bbase = (size_t)((kt >> 3) + l4) * CLS * 8;
        #pragma unroll
        for (int n = 0; n < 4; ++n) {
            bf16x8 b = *(const bf16x8*)&W2p[bbase + (size_t)(n * 16 + l15) * 8];
            acc[n] = __builtin_amdgcn_mfma_f32_16x16x32_bf16(a, b, acc[n], 0, 0, 0);
        }
    }
    float b2c[4];
    #pragma unroll
    for (int n = 0; n < 4; ++n) b2c[n] = b2[n * 16 + l15];
    #pragma unroll
    for (int r = 0; r < 4; ++r) {
        int row = r0 + l4 * 4 + r;
        if (row < Nn) {
            float dv = dinv[row];
            #pragma unroll
            for (int n = 0; n < 4; ++n)
                hs2[(size_t)row * CLS + n * 16 + l15] = f2bf((acc[n][r] + b2c[n]) * dv);
        }
    }
}

// ---------------- Agg2 + log_softmax: quarter-split wave, 4 edges in flight ----------------
__global__ __launch_bounds__(64) void k_agg2(
        const unsigned short* __restrict__ hs2, const int* __restrict__ csr,
        const int* __restrict__ rs, const float* __restrict__ dinv,
        float* __restrict__ out) {
    int d = blockIdx.x, lane = threadIdx.x;
    int q = lane >> 4, c4 = lane & 15;
    int base = rs[d], cnt = rs[d + 1] - base;
    float a0 = 0.f, a1 = 0.f, a2 = 0.f, a3 = 0.f;
    if (q == 0) {  // self loop
        ushort4 v = *(const ushort4*)&hs2[(size_t)d * CLS + c4 * 4];
        a0 = bf2f(v.x); a1 = bf2f(v.y); a2 = bf2f(v.z); a3 = bf2f(v.w);
    }
    int t = q;
    for (; t + 4 < cnt; t += 8) {
        int s0 = csr[base + t];
        int s1 = csr[base + t + 4];
        ushort4 v0 = *(const ushort4*)&hs2[(size_t)s0 * CLS + c4 * 4];
        ushort4 v1 = *(const ushort4*)&hs2[(size_t)s1 * CLS + c4 * 4];
        a0 += bf2f(v0.x) + bf2f(v1.x);
        a1 += bf2f(v0.y) + bf2f(v1.y);
        a2 += bf2f(v0.z) + bf2f(v1.z);
        a3 += bf2f(v0.w) + bf2f(v1.w);
    }
    if (t < cnt) {
        int s0 = csr[base + t];
        ushort4 v0 = *(const ushort4*)&hs2[(size_t)s0 * CLS + c4 * 4];
        a0 += bf2f(v0.x); a1 += bf2f(v0.y); a2 += bf2f(v0.z); a3 += bf2f(v0.w);
    }
    // reduce across quarters (lanes l, l^16, l^32, l^48)
    a0 += __shfl_xor(a0, 16); a0 += __shfl_xor(a0, 32);
    a1 += __shfl_xor(a1, 16); a1 += __shfl_xor(a1, 32);
    a2 += __shfl_xor(a2, 16); a2 += __shfl_xor(a2, 32);
    a3 += __shfl_xor(a3, 16); a3 += __shfl_xor(a3, 32);
    float dv = dinv[d];
    float y0 = a0 * dv, y1 = a1 * dv, y2 = a2 * dv, y3 = a3 * dv;
    float m = fmaxf(fmaxf(y0, y1), fmaxf(y2, y3));
    #pragma unroll
    for (int o = 1; o <= 8; o <<= 1) m = fmaxf(m, __shfl_xor(m, o));
    float s = __expf(y0 - m) + __expf(y1 - m) + __expf(y2 - m) + __expf(y3 - m);
    #pragma unroll
    for (int o = 1; o <= 8; o <<= 1) s += __shfl_xor(s, o);
    if (q == 0) {
        float lg = __logf(s);
        float4 o4 = make_float4(y0 - m - lg, y1 - m - lg, y2 - m - lg, y3 - m - lg);
        *(float4*)&out[(size_t)d * CLS + c4 * 4] = o4;
    }
}

extern "C" void kernel_launch(void* const* d_in, const int* in_sizes, int n_in,
                              void* d_out, int out_size, void* d_ws, size_t ws_size,
                              hipStream_t stream) {
    const float* x  = (const float*)d_in[0];
    const int* ei   = (const int*)d_in[1];
    const float* W1 = (const float*)d_in[2];
    const float* b1 = (const float*)d_in[3];
    const float* W2 = (const float*)d_in[4];
    const float* b2 = (const float*)d_in[5];
    float* out = (float*)d_out;

    const int N = in_sizes[0] / FIN;
    const int E = in_sizes[1] / 2;
    const int* srcp = ei;
    const int* dstp = ei + E;

    char* w = (char*)d_ws;
    auto alloc = [&](size_t bytes) -> void* {
        void* p = (void*)w;
        w += (bytes + 255) / 256 * 256;
        return p;
    };
    int* degi   = (int*)alloc((size_t)N * 4);
    int* rs     = (int*)alloc((size_t)(N + 1) * 4);
    int* cursor = (int*)alloc((size_t)N * 4);
    int* bsum   = (int*)alloc(1024 * 4);
    float* dinv = (float*)alloc((size_t)N * 4);
    int* csr    = (int*)alloc((size_t)E * 4);
    unsigned short* hs1  = (unsigned short*)alloc((size_t)N * HID * 2);
    unsigned short* h2in = (unsigned short*)alloc((size_t)N * HID * 2);
    unsigned short* hs2  = (unsigned short*)alloc((size_t)N * CLS * 2);
    unsigned short* W1p  = (unsigned short*)alloc((size_t)FIN * HID * 2);
    unsigned short* W2p  = (unsigned short*)alloc((size_t)HID * CLS * 2);

    const int nbE = (E + 255) / 256;
    const int nbN = (N + 255) / 256;

    hipMemsetAsync(degi, 0, (size_t)N * 4, stream);
    k_deg<<<nbE, 256, 0, stream>>>(dstp, degi, E);
    k_bsum<<<nbN, 256, 0, stream>>>(degi, bsum, N);
    k_scan<<<nbN, 256, 0, stream>>>(degi, bsum, rs, cursor, dinv, N, E);
    k_scatter<<<nbE, 256, 0, stream>>>(srcp, dstp, cursor, csr, E);
    k_wpack<<<(FIN * HID + 255) / 256, 256, 0, stream>>>(W1, W1p, FIN, HID);
    k_wpack<<<(HID * CLS + 255) / 256, 256, 0, stream>>>(W2, W2p, HID, CLS);

    k_gemm1<<<(N + 63) / 64, 512, 0, stream>>>(x, W1p, b1, dinv, hs1, N);
    k_agg1<<<N, 256, 0, stream>>>(hs1, csr, rs, dinv, h2in);
    k_gemm2<<<(N + 63) / 64, 256, 0, stream>>>(h2in, W2p, b2, dinv, hs2, N);
    k_agg2<<<N, 64, 0, stream>>>(hs2, csr, rs, dinv, out);
}

// Round 3
// 531.662 us; speedup vs baseline: 2.4413x; 1.4866x over previous
//
#include <hip/hip_runtime.h>

#define FIN 512
#define HID 256
#define CLS 64

typedef short bf16x8 __attribute__((ext_vector_type(8)));
typedef float f32x4 __attribute__((ext_vector_type(4)));

__device__ __forceinline__ float bf2f(unsigned short u) {
    union { unsigned int i; float f; } c; c.i = ((unsigned int)u) << 16; return c.f;
}
__device__ __forceinline__ unsigned short f2bf(float f) {
    union { float f; unsigned int u; } c; c.f = f;
    unsigned int u = c.u;
    return (unsigned short)((u + 0x7fffu + ((u >> 16) & 1u)) >> 16);
}

// =============== Bucketed CSR build (bucket = dst >> 9, 512 nodes/bucket) ===============

// Pass 1: bucket histogram. LDS-staged, sequential reads only.
__global__ __launch_bounds__(256) void k_hist(const int* __restrict__ dst,
                                              int* __restrict__ bktcnt, int E) {
    __shared__ int h[256];
    h[threadIdx.x] = 0;
    __syncthreads();
    for (int i = blockIdx.x * blockDim.x + threadIdx.x; i < E; i += gridDim.x * blockDim.x)
        atomicAdd(&h[dst[i] >> 9], 1);
    __syncthreads();
    if (h[threadIdx.x]) atomicAdd(&bktcnt[threadIdx.x], h[threadIdx.x]);
}

// Pass 2: single-block exclusive scan over buckets -> bkt_base, bkt_cursor.
__global__ __launch_bounds__(256) void k_bktscan(const int* __restrict__ bktcnt,
                                                 int* __restrict__ bkt_base,
                                                 int* __restrict__ bkt_cursor,
                                                 int* __restrict__ rs,
                                                 int NB, int Nn, int E) {
    __shared__ int sh[256];
    int t = threadIdx.x;
    int v = (t < NB) ? bktcnt[t] : 0;
    sh[t] = v;
    __syncthreads();
    for (int s = 1; s < 256; s <<= 1) {
        int u = (t >= s) ? sh[t - s] : 0;
        __syncthreads();
        sh[t] += u;
        __syncthreads();
    }
    int excl = sh[t] - v;
    if (t < NB) { bkt_base[t] = excl; bkt_cursor[t] = excl; }
    if (t == 0) { bkt_base[NB] = E; rs[Nn] = E; }
}

// Pass 3: bin edges into bucket-contiguous ebuf. One global atomic per (block,bucket).
#define EPB 4096
__global__ __launch_bounds__(256) void k_binscatter(
        const int* __restrict__ src, const int* __restrict__ dst,
        int* __restrict__ bkt_cursor, uint2* __restrict__ ebuf, int E) {
    __shared__ int h[256];
    __shared__ int cb[256];
    int t = threadIdx.x;
    h[t] = 0;
    __syncthreads();
    int base = blockIdx.x * EPB;
    int es[16], ed[16], lp[16];
    #pragma unroll
    for (int it = 0; it < 16; ++it) {
        int i = base + it * 256 + t;
        if (i < E) {
            es[it] = src[i];
            ed[it] = dst[i];
            lp[it] = atomicAdd(&h[ed[it] >> 9], 1);
        } else {
            es[it] = -1; ed[it] = 0; lp[it] = 0;
        }
    }
    __syncthreads();
    int c = h[t];
    if (c) cb[t] = atomicAdd(&bkt_cursor[t], c);
    __syncthreads();
    #pragma unroll
    for (int it = 0; it < 16; ++it) {
        if (es[it] >= 0) {
            int b = ed[it] >> 9;
            ebuf[cb[b] + lp[it]] = make_uint2((unsigned)es[it], (unsigned)ed[it]);
        }
    }
}

// Pass 4: one block per bucket. LDS degree count -> scan -> rs/dinv, then local scatter.
__global__ __launch_bounds__(256) void k_csrbuild(
        const uint2* __restrict__ ebuf, const int* __restrict__ bkt_base,
        int* __restrict__ rs, float* __restrict__ dinv, int* __restrict__ csr, int Nn) {
    __shared__ int deg[512];
    __shared__ int cur[512];
    __shared__ int ts[256];
    int b = blockIdx.x, t = threadIdx.x;
    int e0 = bkt_base[b], e1 = bkt_base[b + 1];
    int node0 = b << 9;
    deg[t] = 0; deg[t + 256] = 0;
    __syncthreads();
    for (int j = e0 + t; j < e1; j += 256)
        atomicAdd(&deg[(int)ebuf[j].y - node0], 1);
    __syncthreads();
    int d0 = deg[2 * t], d1 = deg[2 * t + 1];
    ts[t] = d0 + d1;
    __syncthreads();
    for (int s = 1; s < 256; s <<= 1) {
        int u = (t >= s) ? ts[t - s] : 0;
        __syncthreads();
        ts[t] += u;
        __syncthreads();
    }
    int excl = ts[t] - (d0 + d1);
    cur[2 * t] = excl;
    cur[2 * t + 1] = excl + d0;
    int n0 = node0 + 2 * t;
    if (n0 < Nn)     { rs[n0]     = e0 + excl;      dinv[n0]     = rsqrtf((float)(d0 + 1)); }
    if (n0 + 1 < Nn) { rs[n0 + 1] = e0 + excl + d0; dinv[n0 + 1] = rsqrtf((float)(d1 + 1)); }
    __syncthreads();
    for (int j = e0 + t; j < e1; j += 256) {
        uint2 e = ebuf[j];
        int p = atomicAdd(&cur[(int)e.y - node0], 1);
        csr[e0 + p] = (int)e.x;
    }
}

// ---------------- Weight pack: (k,n) -> Wp[((k>>3)*Ncols + n)*8 + (k&7)] ----------------
__global__ void k_wpack(const float* __restrict__ W, unsigned short* __restrict__ Wp,
                        int K, int Ncols) {
    int i = blockIdx.x * blockDim.x + threadIdx.x;
    if (i < K * Ncols) {
        int k = i / Ncols, n = i - k * Ncols;
        Wp[((size_t)(k >> 3) * Ncols + n) * 8 + (k & 7)] = f2bf(W[i]);
    }
}

// ---------------- GEMM1 (MFMA bf16): hs1 = (x @ W1 + b1) * dinv[row] ----------------
__global__ __launch_bounds__(512) void k_gemm1(
        const float* __restrict__ x, const unsigned short* __restrict__ W1p,
        const float* __restrict__ b1, const float* __restrict__ dinv,
        unsigned short* __restrict__ hs1, int Nn) {
    __shared__ unsigned short As[64][40];
    int tid = threadIdx.x;
    int w = tid >> 6, lane = tid & 63;
    int wr = w >> 2, wc = w & 3;
    int l15 = lane & 15, l4 = lane >> 4;
    int row0 = blockIdx.x * 64;

    f32x4 zero = {0.f, 0.f, 0.f, 0.f};
    f32x4 acc[2][4];
    #pragma unroll
    for (int m = 0; m < 2; ++m)
        #pragma unroll
        for (int n = 0; n < 4; ++n) acc[m][n] = zero;

    int sr = tid >> 3;
    int sc = tid & 7;
    bool srok = (row0 + sr) < Nn;
    const float* xrow = x + (size_t)(row0 + sr) * FIN + sc * 4;

    for (int kt = 0; kt < FIN; kt += 32) {
        float4 v = srok ? *(const float4*)(xrow + kt) : make_float4(0.f, 0.f, 0.f, 0.f);
        ushort4 o;
        o.x = f2bf(v.x); o.y = f2bf(v.y); o.z = f2bf(v.z); o.w = f2bf(v.w);
        *(ushort4*)&As[sr][sc * 4] = o;
        __syncthreads();

        bf16x8 bfr[4];
        size_t bbase = (size_t)((kt >> 3) + l4) * HID * 8;
        #pragma unroll
        for (int n = 0; n < 4; ++n) {
            int col = wc * 64 + n * 16 + l15;
            bfr[n] = *(const bf16x8*)&W1p[bbase + (size_t)col * 8];
        }
        bf16x8 afr[2];
        #pragma unroll
        for (int m = 0; m < 2; ++m) {
            int r = wr * 32 + m * 16 + l15;
            afr[m] = *(const bf16x8*)&As[r][l4 * 8];
        }
        #pragma unroll
        for (int m = 0; m < 2; ++m)
            #pragma unroll
            for (int n = 0; n < 4; ++n)
                acc[m][n] = __builtin_amdgcn_mfma_f32_16x16x32_bf16(
                    afr[m], bfr[n], acc[m][n], 0, 0, 0);
        __syncthreads();
    }

    float b1c[4];
    #pragma unroll
    for (int n = 0; n < 4; ++n) b1c[n] = b1[wc * 64 + n * 16 + l15];
    #pragma unroll
    for (int m = 0; m < 2; ++m) {
        #pragma unroll
        for (int r = 0; r < 4; ++r) {
            int row = row0 + wr * 32 + m * 16 + l4 * 4 + r;
            if (row < Nn) {
                float dv = dinv[row];
                #pragma unroll
                for (int n = 0; n < 4; ++n) {
                    int col = wc * 64 + n * 16 + l15;
                    hs1[(size_t)row * HID + col] = f2bf((acc[m][n][r] + b1c[n]) * dv);
                }
            }
        }
    }
}

// ---------------- Agg1: h2in[d] = relu(dinv[d]*(sum_s hs1[s] + hs1[d])), 4 waves/dst ----------------
__global__ __launch_bounds__(256) void k_agg1(
        const unsigned short* __restrict__ hs1, const int* __restrict__ csr,
        const int* __restrict__ rs, const float* __restrict__ dinv,
        unsigned short* __restrict__ h2in) {
    __shared__ float sh[4][256];
    int d = blockIdx.x;
    int tid = threadIdx.x;
    int q = tid >> 6, lane = tid & 63;
    int base = rs[d], cnt = rs[d + 1] - base;
    float a0 = 0.f, a1 = 0.f, a2 = 0.f, a3 = 0.f;
    if (q == 0) {
        ushort4 v = *(const ushort4*)&hs1[(size_t)d * HID + lane * 4];
        a0 = bf2f(v.x); a1 = bf2f(v.y); a2 = bf2f(v.z); a3 = bf2f(v.w);
    }
    int t = q;
    for (; t + 4 < cnt; t += 8) {
        int s0 = csr[base + t];
        int s1 = csr[base + t + 4];
        ushort4 v0 = *(const ushort4*)&hs1[(size_t)s0 * HID + lane * 4];
        ushort4 v1 = *(const ushort4*)&hs1[(size_t)s1 * HID + lane * 4];
        a0 += bf2f(v0.x) + bf2f(v1.x);
        a1 += bf2f(v0.y) + bf2f(v1.y);
        a2 += bf2f(v0.z) + bf2f(v1.z);
        a3 += bf2f(v0.w) + bf2f(v1.w);
    }
    if (t < cnt) {
        int s0 = csr[base + t];
        ushort4 v0 = *(const ushort4*)&hs1[(size_t)s0 * HID + lane * 4];
        a0 += bf2f(v0.x); a1 += bf2f(v0.y); a2 += bf2f(v0.z); a3 += bf2f(v0.w);
    }
    f32x4 p = {a0, a1, a2, a3};
    *(f32x4*)&sh[q][lane * 4] = p;
    __syncthreads();
    if (tid < 64) {
        f32x4 s0 = *(const f32x4*)&sh[0][tid * 4];
        f32x4 s1 = *(const f32x4*)&sh[1][tid * 4];
        f32x4 s2 = *(const f32x4*)&sh[2][tid * 4];
        f32x4 s3 = *(const f32x4*)&sh[3][tid * 4];
        float dv = dinv[d];
        ushort4 o;
        o.x = f2bf(fmaxf((s0[0] + s1[0] + s2[0] + s3[0]) * dv, 0.f));
        o.y = f2bf(fmaxf((s0[1] + s1[1] + s2[1] + s3[1]) * dv, 0.f));
        o.z = f2bf(fmaxf((s0[2] + s1[2] + s2[2] + s3[2]) * dv, 0.f));
        o.w = f2bf(fmaxf((s0[3] + s1[3] + s2[3] + s3[3]) * dv, 0.f));
        *(ushort4*)&h2in[(size_t)d * HID + tid * 4] = o;
    }
}

// ---------------- GEMM2 (MFMA): hs2 = (h2in @ W2 + b2) * dinv, no LDS ----------------
__global__ __launch_bounds__(256) void k_gemm2(
        const unsigned short* __restrict__ h2in, const unsigned short* __restrict__ W2p,
        const float* __restrict__ b2, const float* __restrict__ dinv,
        unsigned short* __restrict__ hs2, int Nn) {
    int tid = threadIdx.x;
    int w = tid >> 6, lane = tid & 63;
    int l15 = lane & 15, l4 = lane >> 4;
    int r0 = blockIdx.x * 64 + w * 16;
    int arow = r0 + l15;
    bool aok = arow < Nn;
    const unsigned short* ap = h2in + (size_t)arow * HID + l4 * 8;

    f32x4 zero = {0.f, 0.f, 0.f, 0.f};
    bf16x8 zf = {0, 0, 0, 0, 0, 0, 0, 0};
    f32x4 acc[4];
    #pragma unroll
    for (int n = 0; n < 4; ++n) acc[n] = zero;

    #pragma unroll
    for (int kt = 0; kt < HID; kt += 32) {
        bf16x8 a = aok ? *(const bf16x8*)(ap + kt) : zf;
        size_t bbase = (size_t)((kt >> 3) + l4) * CLS * 8;
        #pragma unroll
        for (int n = 0; n < 4; ++n) {
            bf16x8 bb = *(const bf16x8*)&W2p[bbase + (size_t)(n * 16 + l15) * 8];
            acc[n] = __builtin_amdgcn_mfma_f32_16x16x32_bf16(a, bb, acc[n], 0, 0, 0);
        }
    }
    float b2c[4];
    #pragma unroll
    for (int n = 0; n < 4; ++n) b2c[n] = b2[n * 16 + l15];
    #pragma unroll
    for (int r = 0; r < 4; ++r) {
        int row = r0 + l4 * 4 + r;
        if (row < Nn) {
            float dv = dinv[row];
            #pragma unroll
            for (int n = 0; n < 4; ++n)
                hs2[(size_t)row * CLS + n * 16 + l15] = f2bf((acc[n][r] + b2c[n]) * dv);
        }
    }
}

// ---------------- Agg2 + log_softmax: quarter-split wave ----------------
__global__ __launch_bounds__(64) void k_agg2(
        const unsigned short* __restrict__ hs2, const int* __restrict__ csr,
        const int* __restrict__ rs, const float* __restrict__ dinv,
        float* __restrict__ out) {
    int d = blockIdx.x, lane = threadIdx.x;
    int q = lane >> 4, c4 = lane & 15;
    int base = rs[d], cnt = rs[d + 1] - base;
    float a0 = 0.f, a1 = 0.f, a2 = 0.f, a3 = 0.f;
    if (q == 0) {
        ushort4 v = *(const ushort4*)&hs2[(size_t)d * CLS + c4 * 4];
        a0 = bf2f(v.x); a1 = bf2f(v.y); a2 = bf2f(v.z); a3 = bf2f(v.w);
    }
    int t = q;
    for (; t + 4 < cnt; t += 8) {
        int s0 = csr[base + t];
        int s1 = csr[base + t + 4];
        ushort4 v0 = *(const ushort4*)&hs2[(size_t)s0 * CLS + c4 * 4];
        ushort4 v1 = *(const ushort4*)&hs2[(size_t)s1 * CLS + c4 * 4];
        a0 += bf2f(v0.x) + bf2f(v1.x);
        a1 += bf2f(v0.y) + bf2f(v1.y);
        a2 += bf2f(v0.z) + bf2f(v1.z);
        a3 += bf2f(v0.w) + bf2f(v1.w);
    }
    if (t < cnt) {
        int s0 = csr[base + t];
        ushort4 v0 = *(const ushort4*)&hs2[(size_t)s0 * CLS + c4 * 4];
        a0 += bf2f(v0.x); a1 += bf2f(v0.y); a2 += bf2f(v0.z); a3 += bf2f(v0.w);
    }
    a0 += __shfl_xor(a0, 16); a0 += __shfl_xor(a0, 32);
    a1 += __shfl_xor(a1, 16); a1 += __shfl_xor(a1, 32);
    a2 += __shfl_xor(a2, 16); a2 += __shfl_xor(a2, 32);
    a3 += __shfl_xor(a3, 16); a3 += __shfl_xor(a3, 32);
    float dv = dinv[d];
    float y0 = a0 * dv, y1 = a1 * dv, y2 = a2 * dv, y3 = a3 * dv;
    float m = fmaxf(fmaxf(y0, y1), fmaxf(y2, y3));
    #pragma unroll
    for (int o = 1; o <= 8; o <<= 1) m = fmaxf(m, __shfl_xor(m, o));
    float s = __expf(y0 - m) + __expf(y1 - m) + __expf(y2 - m) + __expf(y3 - m);
    #pragma unroll
    for (int o = 1; o <= 8; o <<= 1) s += __shfl_xor(s, o);
    if (q == 0) {
        float lg = __logf(s);
        float4 o4 = make_float4(y0 - m - lg, y1 - m - lg, y2 - m - lg, y3 - m - lg);
        *(float4*)&out[(size_t)d * CLS + c4 * 4] = o4;
    }
}

extern "C" void kernel_launch(void* const* d_in, const int* in_sizes, int n_in,
                              void* d_out, int out_size, void* d_ws, size_t ws_size,
                              hipStream_t stream) {
    const float* x  = (const float*)d_in[0];
    const int* ei   = (const int*)d_in[1];
    const float* W1 = (const float*)d_in[2];
    const float* b1 = (const float*)d_in[3];
    const float* W2 = (const float*)d_in[4];
    const float* b2 = (const float*)d_in[5];
    float* out = (float*)d_out;

    const int N = in_sizes[0] / FIN;
    const int E = in_sizes[1] / 2;
    const int NB = (N + 511) >> 9;          // buckets of 512 nodes (196 for N=100000)
    const int* srcp = ei;
    const int* dstp = ei + E;

    char* w = (char*)d_ws;
    auto alloc = [&](size_t bytes) -> void* {
        void* p = (void*)w;
        w += (bytes + 255) / 256 * 256;
        return p;
    };
    int* rs        = (int*)alloc((size_t)(N + 1) * 4);
    float* dinv    = (float*)alloc((size_t)N * 4);
    int* csr       = (int*)alloc((size_t)E * 4);
    int* bktcnt    = (int*)alloc((size_t)(NB + 1) * 4);
    int* bkt_base  = (int*)alloc((size_t)(NB + 1) * 4);
    int* bkt_cursor= (int*)alloc((size_t)(NB + 1) * 4);
    unsigned short* hs1  = (unsigned short*)alloc((size_t)N * HID * 2);
    unsigned short* h2in = (unsigned short*)alloc((size_t)N * HID * 2);
    unsigned short* hs2  = (unsigned short*)alloc((size_t)N * CLS * 2);
    unsigned short* W1p  = (unsigned short*)alloc((size_t)FIN * HID * 2);
    unsigned short* W2p  = (unsigned short*)alloc((size_t)HID * CLS * 2);
    // ebuf aliases hs1: only live before k_gemm1 writes hs1 (stream-ordered).
    uint2* ebuf = (uint2*)hs1;

    hipMemsetAsync(bktcnt, 0, (size_t)(NB + 1) * 4, stream);
    k_hist<<<1024, 256, 0, stream>>>(dstp, bktcnt, E);
    k_bktscan<<<1, 256, 0, stream>>>(bktcnt, bkt_base, bkt_cursor, rs, NB, N, E);
    k_binscatter<<<(E + EPB - 1) / EPB, 256, 0, stream>>>(srcp, dstp, bkt_cursor, ebuf, E);
    k_csrbuild<<<NB, 256, 0, stream>>>(ebuf, bkt_base, rs, dinv, csr, N);

    k_wpack<<<(FIN * HID + 255) / 256, 256, 0, stream>>>(W1, W1p, FIN, HID);
    k_wpack<<<(HID * CLS + 255) / 256, 256, 0, stream>>>(W2, W2p, HID, CLS);

    k_gemm1<<<(N + 63) / 64, 512, 0, stream>>>(x, W1p, b1, dinv, hs1, N);
    k_agg1<<<N, 256, 0, stream>>>(hs1, csr, rs, dinv, h2in);
    k_gemm2<<<(N + 63) / 64, 256, 0, stream>>>(h2in, W2p, b2, dinv, hs2, N);
    k_agg2<<<N, 64, 0, stream>>>(hs2, csr, rs, dinv, out);
}

// Round 4
// 515.043 us; speedup vs baseline: 2.5201x; 1.0323x over previous
//
#include <hip/hip_runtime.h>

#define FIN 512
#define HID 256
#define CLS 64
#define PAD 8
#define BKT_SLACK 3584   // 512 nodes * 7 max pad per node

typedef short bf16x8 __attribute__((ext_vector_type(8)));
typedef float f32x4 __attribute__((ext_vector_type(4)));

__device__ __forceinline__ float bf2f(unsigned short u) {
    union { unsigned int i; float f; } c; c.i = ((unsigned int)u) << 16; return c.f;
}
__device__ __forceinline__ unsigned short f2bf(float f) {
    union { float f; unsigned int u; } c; c.f = f;
    unsigned int u = c.u;
    return (unsigned short)((u + 0x7fffu + ((u >> 16) & 1u)) >> 16);
}

// =============== Bucketed CSR build (bucket = dst >> 9, 512 nodes/bucket) ===============

__global__ __launch_bounds__(256) void k_hist(const int* __restrict__ dst,
                                              int* __restrict__ bktcnt, int E) {
    __shared__ int h[256];
    h[threadIdx.x] = 0;
    __syncthreads();
    for (int i = blockIdx.x * blockDim.x + threadIdx.x; i < E; i += gridDim.x * blockDim.x)
        atomicAdd(&h[dst[i] >> 9], 1);
    __syncthreads();
    if (h[threadIdx.x]) atomicAdd(&bktcnt[threadIdx.x], h[threadIdx.x]);
}

__global__ __launch_bounds__(256) void k_bktscan(const int* __restrict__ bktcnt,
                                                 int* __restrict__ bkt_base,
                                                 int* __restrict__ bkt_cursor,
                                                 int NB, int E) {
    __shared__ int sh[256];
    int t = threadIdx.x;
    int v = (t < NB) ? bktcnt[t] : 0;
    sh[t] = v;
    __syncthreads();
    for (int s = 1; s < 256; s <<= 1) {
        int u = (t >= s) ? sh[t - s] : 0;
        __syncthreads();
        sh[t] += u;
        __syncthreads();
    }
    int excl = sh[t] - v;
    if (t < NB) { bkt_base[t] = excl; bkt_cursor[t] = excl; }
    if (t == 0) bkt_base[NB] = E;
}

#define EPB 4096
__global__ __launch_bounds__(256) void k_binscatter(
        const int* __restrict__ src, const int* __restrict__ dst,
        int* __restrict__ bkt_cursor, uint2* __restrict__ ebuf, int E) {
    __shared__ int h[256];
    __shared__ int cb[256];
    int t = threadIdx.x;
    h[t] = 0;
    __syncthreads();
    int base = blockIdx.x * EPB;
    int es[16], ed[16], lp[16];
    #pragma unroll
    for (int it = 0; it < 16; ++it) {
        int i = base + it * 256 + t;
        if (i < E) {
            es[it] = src[i];
            ed[it] = dst[i];
            lp[it] = atomicAdd(&h[ed[it] >> 9], 1);
        } else {
            es[it] = -1; ed[it] = 0; lp[it] = 0;
        }
    }
    __syncthreads();
    int c = h[t];
    if (c) cb[t] = atomicAdd(&bkt_cursor[t], c);
    __syncthreads();
    #pragma unroll
    for (int it = 0; it < 16; ++it) {
        if (es[it] >= 0) {
            int b = ed[it] >> 9;
            ebuf[cb[b] + lp[it]] = make_uint2((unsigned)es[it], (unsigned)ed[it]);
        }
    }
}

// One block per bucket. Degrees -> PADDED scan -> rs/cnte/dinv, scatter + pad fill.
__global__ __launch_bounds__(256) void k_csrbuild(
        const uint2* __restrict__ ebuf, const int* __restrict__ bkt_base,
        int* __restrict__ rs, int* __restrict__ cnte, float* __restrict__ dinv,
        int* __restrict__ csr, int Nn) {
    __shared__ int deg[512];
    __shared__ int cur[512];
    __shared__ int ts[256];
    int b = blockIdx.x, t = threadIdx.x;
    int e0 = bkt_base[b], e1 = bkt_base[b + 1];
    int pb = e0 + b * BKT_SLACK;        // padded absolute base of this bucket in csr
    int node0 = b << 9;
    deg[t] = 0; deg[t + 256] = 0;
    __syncthreads();
    for (int j = e0 + t; j < e1; j += 256)
        atomicAdd(&deg[(int)ebuf[j].y - node0], 1);
    __syncthreads();
    int d0 = deg[2 * t], d1 = deg[2 * t + 1];
    int p0 = (d0 + PAD - 1) & ~(PAD - 1);
    int p1 = (d1 + PAD - 1) & ~(PAD - 1);
    ts[t] = p0 + p1;
    __syncthreads();
    for (int s = 1; s < 256; s <<= 1) {
        int u = (t >= s) ? ts[t - s] : 0;
        __syncthreads();
        ts[t] += u;
        __syncthreads();
    }
    int excl = ts[t] - (p0 + p1);
    cur[2 * t] = excl;
    cur[2 * t + 1] = excl + p0;
    int n0 = node0 + 2 * t;
    if (n0 < Nn)     { rs[n0]     = pb + excl;      cnte[n0]     = p0; dinv[n0]     = rsqrtf((float)(d0 + 1)); }
    if (n0 + 1 < Nn) { rs[n0 + 1] = pb + excl + p0; cnte[n0 + 1] = p1; dinv[n0 + 1] = rsqrtf((float)(d1 + 1)); }
    __syncthreads();
    for (int j = e0 + t; j < e1; j += 256) {
        uint2 e = ebuf[j];
        int p = atomicAdd(&cur[(int)e.y - node0], 1);
        csr[pb + p] = (int)e.x;
    }
    // pad-fill: dummy node index Nn (zeroed row)
    for (int j = d0; j < p0; ++j) csr[pb + excl + j] = Nn;
    for (int j = d1; j < p1; ++j) csr[pb + excl + p0 + j] = Nn;
}

// ---------------- Weight pack: (k,n) -> Wp[((k>>3)*Ncols + n)*8 + (k&7)] ----------------
__global__ void k_wpack(const float* __restrict__ W, unsigned short* __restrict__ Wp,
                        int K, int Ncols) {
    int i = blockIdx.x * blockDim.x + threadIdx.x;
    if (i < K * Ncols) {
        int k = i / Ncols, n = i - k * Ncols;
        Wp[((size_t)(k >> 3) * Ncols + n) * 8 + (k & 7)] = f2bf(W[i]);
    }
}

// ---------------- GEMM1 (MFMA bf16): hs1 = (x @ W1 + b1) * dinv[row] ----------------
__global__ __launch_bounds__(512) void k_gemm1(
        const float* __restrict__ x, const unsigned short* __restrict__ W1p,
        const float* __restrict__ b1, const float* __restrict__ dinv,
        unsigned short* __restrict__ hs1, int Nn) {
    __shared__ unsigned short As[64][40];
    int tid = threadIdx.x;
    int w = tid >> 6, lane = tid & 63;
    int wr = w >> 2, wc = w & 3;
    int l15 = lane & 15, l4 = lane >> 4;
    int row0 = blockIdx.x * 64;

    f32x4 zero = {0.f, 0.f, 0.f, 0.f};
    f32x4 acc[2][4];
    #pragma unroll
    for (int m = 0; m < 2; ++m)
        #pragma unroll
        for (int n = 0; n < 4; ++n) acc[m][n] = zero;

    int sr = tid >> 3;
    int sc = tid & 7;
    bool srok = (row0 + sr) < Nn;
    const float* xrow = x + (size_t)(row0 + sr) * FIN + sc * 4;

    for (int kt = 0; kt < FIN; kt += 32) {
        float4 v = srok ? *(const float4*)(xrow + kt) : make_float4(0.f, 0.f, 0.f, 0.f);
        ushort4 o;
        o.x = f2bf(v.x); o.y = f2bf(v.y); o.z = f2bf(v.z); o.w = f2bf(v.w);
        *(ushort4*)&As[sr][sc * 4] = o;
        __syncthreads();

        bf16x8 bfr[4];
        size_t bbase = (size_t)((kt >> 3) + l4) * HID * 8;
        #pragma unroll
        for (int n = 0; n < 4; ++n) {
            int col = wc * 64 + n * 16 + l15;
            bfr[n] = *(const bf16x8*)&W1p[bbase + (size_t)col * 8];
        }
        bf16x8 afr[2];
        #pragma unroll
        for (int m = 0; m < 2; ++m) {
            int r = wr * 32 + m * 16 + l15;
            afr[m] = *(const bf16x8*)&As[r][l4 * 8];
        }
        #pragma unroll
        for (int m = 0; m < 2; ++m)
            #pragma unroll
            for (int n = 0; n < 4; ++n)
                acc[m][n] = __builtin_amdgcn_mfma_f32_16x16x32_bf16(
                    afr[m], bfr[n], acc[m][n], 0, 0, 0);
        __syncthreads();
    }

    float b1c[4];
    #pragma unroll
    for (int n = 0; n < 4; ++n) b1c[n] = b1[wc * 64 + n * 16 + l15];
    #pragma unroll
    for (int m = 0; m < 2; ++m) {
        #pragma unroll
        for (int r = 0; r < 4; ++r) {
            int row = row0 + wr * 32 + m * 16 + l4 * 4 + r;
            if (row < Nn) {
                float dv = dinv[row];
                #pragma unroll
                for (int n = 0; n < 4; ++n) {
                    int col = wc * 64 + n * 16 + l15;
                    hs1[(size_t)row * HID + col] = f2bf((acc[m][n][r] + b1c[n]) * dv);
                }
            }
        }
    }
}

// ---------------- Agg1: one wave per dst, 8-edge chunks, double-buffered ----------------
__global__ __launch_bounds__(256) void k_agg1(
        const unsigned short* __restrict__ hs1, const int* __restrict__ csr,
        const int* __restrict__ rs, const int* __restrict__ cnte,
        const float* __restrict__ dinv, unsigned short* __restrict__ h2in, int Nn) {
    int d = blockIdx.x * 4 + (threadIdx.x >> 6);
    if (d >= Nn) return;
    int lane = threadIdx.x & 63;
    size_t loff = (size_t)lane * 4;
    ushort4 sv = *(const ushort4*)&hs1[(size_t)d * HID + loff];
    float a0 = bf2f(sv.x), a1 = bf2f(sv.y), a2 = bf2f(sv.z), a3 = bf2f(sv.w);
    int base = rs[d], cnt = cnte[d];
    const int* cp = csr + base;
    if (cnt > 0) {
        ushort4 wA[8], wB[8];
        #pragma unroll
        for (int i = 0; i < 8; ++i)
            wA[i] = *(const ushort4*)&hs1[(size_t)cp[i] * HID + loff];
        for (int t = 8; t + 8 <= cnt; t += 8) {
            #pragma unroll
            for (int i = 0; i < 8; ++i)
                wB[i] = *(const ushort4*)&hs1[(size_t)cp[t + i] * HID + loff];
            #pragma unroll
            for (int i = 0; i < 8; ++i) {
                a0 += bf2f(wA[i].x); a1 += bf2f(wA[i].y);
                a2 += bf2f(wA[i].z); a3 += bf2f(wA[i].w);
            }
            #pragma unroll
            for (int i = 0; i < 8; ++i) wA[i] = wB[i];
        }
        #pragma unroll
        for (int i = 0; i < 8; ++i) {
            a0 += bf2f(wA[i].x); a1 += bf2f(wA[i].y);
            a2 += bf2f(wA[i].z); a3 += bf2f(wA[i].w);
        }
    }
    float dv = dinv[d];
    ushort4 o;
    o.x = f2bf(fmaxf(a0 * dv, 0.f));
    o.y = f2bf(fmaxf(a1 * dv, 0.f));
    o.z = f2bf(fmaxf(a2 * dv, 0.f));
    o.w = f2bf(fmaxf(a3 * dv, 0.f));
    *(ushort4*)&h2in[(size_t)d * HID + loff] = o;
}

// ---------------- GEMM2 (MFMA): hs2 = (h2in @ W2 + b2) * dinv, no LDS ----------------
__global__ __launch_bounds__(256) void k_gemm2(
        const unsigned short* __restrict__ h2in, const unsigned short* __restrict__ W2p,
        const float* __restrict__ b2, const float* __restrict__ dinv,
        unsigned short* __restrict__ hs2, int Nn) {
    int tid = threadIdx.x;
    int w = tid >> 6, lane = tid & 63;
    int l15 = lane & 15, l4 = lane >> 4;
    int r0 = blockIdx.x * 64 + w * 16;
    int arow = r0 + l15;
    bool aok = arow < Nn;
    const unsigned short* ap = h2in + (size_t)arow * HID + l4 * 8;

    f32x4 zero = {0.f, 0.f, 0.f, 0.f};
    bf16x8 zf = {0, 0, 0, 0, 0, 0, 0, 0};
    f32x4 acc[4];
    #pragma unroll
    for (int n = 0; n < 4; ++n) acc[n] = zero;

    #pragma unroll
    for (int kt = 0; kt < HID; kt += 32) {
        bf16x8 a = aok ? *(const bf16x8*)(ap + kt) : zf;
        size_t bbase = (size_t)((kt >> 3) + l4) * CLS * 8;
        #pragma unroll
        for (int n = 0; n < 4; ++n) {
            bf16x8 bb = *(const bf16x8*)&W2p[bbase + (size_t)(n * 16 + l15) * 8];
            acc[n] = __builtin_amdgcn_mfma_f32_16x16x32_bf16(a, bb, acc[n], 0, 0, 0);
        }
    }
    float b2c[4];
    #pragma unroll
    for (int n = 0; n < 4; ++n) b2c[n] = b2[n * 16 + l15];
    #pragma unroll
    for (int r = 0; r < 4; ++r) {
        int row = r0 + l4 * 4 + r;
        if (row < Nn) {
            float dv = dinv[row];
            #pragma unroll
            for (int n = 0; n < 4; ++n)
                hs2[(size_t)row * CLS + n * 16 + l15] = f2bf((acc[n][r] + b2c[n]) * dv);
        }
    }
}

// ---------------- Agg2 + log_softmax: one wave/dst, quarter-split, 16-edge chunks ----------------
__global__ __launch_bounds__(256) void k_agg2(
        const unsigned short* __restrict__ hs2, const int* __restrict__ csr,
        const int* __restrict__ rs, const int* __restrict__ cnte,
        const float* __restrict__ dinv, float* __restrict__ out, int Nn) {
    int d = blockIdx.x * 4 + (threadIdx.x >> 6);
    if (d >= Nn) return;
    int lane = threadIdx.x & 63;
    int q = lane >> 4, c4 = lane & 15;
    size_t loff = (size_t)c4 * 4;
    float a0 = 0.f, a1 = 0.f, a2 = 0.f, a3 = 0.f;
    if (q == 0) {
        ushort4 v = *(const ushort4*)&hs2[(size_t)d * CLS + loff];
        a0 = bf2f(v.x); a1 = bf2f(v.y); a2 = bf2f(v.z); a3 = bf2f(v.w);
    }
    int base = rs[d], cnt = cnte[d];
    const int* cp = csr + base;
    int t = 0;
    for (; t + 16 <= cnt; t += 16) {
        int s0 = cp[t + q], s1 = cp[t + q + 4], s2 = cp[t + q + 8], s3 = cp[t + q + 12];
        ushort4 v0 = *(const ushort4*)&hs2[(size_t)s0 * CLS + loff];
        ushort4 v1 = *(const ushort4*)&hs2[(size_t)s1 * CLS + loff];
        ushort4 v2 = *(const ushort4*)&hs2[(size_t)s2 * CLS + loff];
        ushort4 v3 = *(const ushort4*)&hs2[(size_t)s3 * CLS + loff];
        a0 += bf2f(v0.x) + bf2f(v1.x) + bf2f(v2.x) + bf2f(v3.x);
        a1 += bf2f(v0.y) + bf2f(v1.y) + bf2f(v2.y) + bf2f(v3.y);
        a2 += bf2f(v0.z) + bf2f(v1.z) + bf2f(v2.z) + bf2f(v3.z);
        a3 += bf2f(v0.w) + bf2f(v1.w) + bf2f(v2.w) + bf2f(v3.w);
    }
    if (t < cnt) {  // exactly 8 remain (cnt is a multiple of 8)
        int s0 = cp[t + q], s1 = cp[t + q + 4];
        ushort4 v0 = *(const ushort4*)&hs2[(size_t)s0 * CLS + loff];
        ushort4 v1 = *(const ushort4*)&hs2[(size_t)s1 * CLS + loff];
        a0 += bf2f(v0.x) + bf2f(v1.x);
        a1 += bf2f(v0.y) + bf2f(v1.y);
        a2 += bf2f(v0.z) + bf2f(v1.z);
        a3 += bf2f(v0.w) + bf2f(v1.w);
    }
    a0 += __shfl_xor(a0, 16); a0 += __shfl_xor(a0, 32);
    a1 += __shfl_xor(a1, 16); a1 += __shfl_xor(a1, 32);
    a2 += __shfl_xor(a2, 16); a2 += __shfl_xor(a2, 32);
    a3 += __shfl_xor(a3, 16); a3 += __shfl_xor(a3, 32);
    float dv = dinv[d];
    float y0 = a0 * dv, y1 = a1 * dv, y2 = a2 * dv, y3 = a3 * dv;
    float m = fmaxf(fmaxf(y0, y1), fmaxf(y2, y3));
    #pragma unroll
    for (int o = 1; o <= 8; o <<= 1) m = fmaxf(m, __shfl_xor(m, o));
    float s = __expf(y0 - m) + __expf(y1 - m) + __expf(y2 - m) + __expf(y3 - m);
    #pragma unroll
    for (int o = 1; o <= 8; o <<= 1) s += __shfl_xor(s, o);
    if (q == 0) {
        float lg = __logf(s);
        float4 o4 = make_float4(y0 - m - lg, y1 - m - lg, y2 - m - lg, y3 - m - lg);
        *(float4*)&out[(size_t)d * CLS + c4 * 4] = o4;
    }
}

extern "C" void kernel_launch(void* const* d_in, const int* in_sizes, int n_in,
                              void* d_out, int out_size, void* d_ws, size_t ws_size,
                              hipStream_t stream) {
    const float* x  = (const float*)d_in[0];
    const int* ei   = (const int*)d_in[1];
    const float* W1 = (const float*)d_in[2];
    const float* b1 = (const float*)d_in[3];
    const float* W2 = (const float*)d_in[4];
    const float* b2 = (const float*)d_in[5];
    float* out = (float*)d_out;

    const int N = in_sizes[0] / FIN;
    const int E = in_sizes[1] / 2;
    const int NB = (N + 511) >> 9;
    const int* srcp = ei;
    const int* dstp = ei + E;

    char* w = (char*)d_ws;
    auto alloc = [&](size_t bytes) -> void* {
        void* p = (void*)w;
        w += (bytes + 255) / 256 * 256;
        return p;
    };
    int* rs        = (int*)alloc((size_t)(N + 1) * 4);
    int* cnte      = (int*)alloc((size_t)N * 4);
    float* dinv    = (float*)alloc((size_t)N * 4);
    int* csr       = (int*)alloc(((size_t)E + (size_t)NB * BKT_SLACK + 8) * 4);
    int* bktcnt    = (int*)alloc((size_t)(NB + 1) * 4);
    int* bkt_base  = (int*)alloc((size_t)(NB + 1) * 4);
    int* bkt_cursor= (int*)alloc((size_t)(NB + 1) * 4);
    unsigned short* hs1  = (unsigned short*)alloc((size_t)(N + 1) * HID * 2);  // +1 dummy zero row
    unsigned short* h2in = (unsigned short*)alloc((size_t)N * HID * 2);
    unsigned short* hs2  = (unsigned short*)alloc((size_t)(N + 1) * CLS * 2);  // +1 dummy zero row
    unsigned short* W1p  = (unsigned short*)alloc((size_t)FIN * HID * 2);
    unsigned short* W2p  = (unsigned short*)alloc((size_t)HID * CLS * 2);
    // ebuf aliases hs1's first 25.6 MB: dead before k_gemm1 writes hs1 (stream-ordered).
    uint2* ebuf = (uint2*)hs1;

    hipMemsetAsync(bktcnt, 0, (size_t)(NB + 1) * 4, stream);
    hipMemsetAsync(hs1 + (size_t)N * HID, 0, HID * 2, stream);  // dummy row (beyond ebuf range)
    hipMemsetAsync(hs2 + (size_t)N * CLS, 0, CLS * 2, stream);

    k_hist<<<1024, 256, 0, stream>>>(dstp, bktcnt, E);
    k_bktscan<<<1, 256, 0, stream>>>(bktcnt, bkt_base, bkt_cursor, NB, E);
    k_binscatter<<<(E + EPB - 1) / EPB, 256, 0, stream>>>(srcp, dstp, bkt_cursor, ebuf, E);
    k_csrbuild<<<NB, 256, 0, stream>>>(ebuf, bkt_base, rs, cnte, dinv, csr, N);

    k_wpack<<<(FIN * HID + 255) / 256, 256, 0, stream>>>(W1, W1p, FIN, HID);
    k_wpack<<<(HID * CLS + 255) / 256, 256, 0, stream>>>(W2, W2p, HID, CLS);

    k_gemm1<<<(N + 63) / 64, 512, 0, stream>>>(x, W1p, b1, dinv, hs1, N);
    k_agg1<<<(N + 3) / 4, 256, 0, stream>>>(hs1, csr, rs, cnte, dinv, h2in, N);
    k_gemm2<<<(N + 63) / 64, 256, 0, stream>>>(h2in, W2p, b2, dinv, hs2, N);
    k_agg2<<<(N + 3) / 4, 256, 0, stream>>>(hs2, csr, rs, cnte, dinv, out, N);
}

// Round 5
// 404.326 us; speedup vs baseline: 3.2102x; 1.2738x over previous
//
#include <hip/hip_runtime.h>

#define FIN 512
#define HID 256
#define CLS 64
#define PAD 8
#define BKT_SLACK 4096   // 512 nodes * up to 8 extra slots (self + pad7)

typedef short bf16x8 __attribute__((ext_vector_type(8)));
typedef float f32x4 __attribute__((ext_vector_type(4)));
typedef float f32x2 __attribute__((ext_vector_type(2)));

__device__ __forceinline__ float bf2f(unsigned short u) {
    union { unsigned int i; float f; } c; c.i = ((unsigned int)u) << 16; return c.f;
}
__device__ __forceinline__ unsigned short f2bf(float f) {
    union { float f; unsigned int u; } c; c.f = f;
    unsigned int u = c.u;
    return (unsigned short)((u + 0x7fffu + ((u >> 16) & 1u)) >> 16);
}
__device__ __forceinline__ unsigned char f2fp8(float v) {  // e4m3 via HW cvt
    int r = __builtin_amdgcn_cvt_pk_fp8_f32(v, v, 0, false);
    return (unsigned char)(r & 0xFF);
}

// =============== Bucketed CSR build (bucket = dst >> 9, 512 nodes/bucket) ===============

__global__ __launch_bounds__(256) void k_hist(const int* __restrict__ dst,
                                              int* __restrict__ bktcnt, int E) {
    __shared__ int h[256];
    h[threadIdx.x] = 0;
    __syncthreads();
    for (int i = blockIdx.x * blockDim.x + threadIdx.x; i < E; i += gridDim.x * blockDim.x)
        atomicAdd(&h[dst[i] >> 9], 1);
    __syncthreads();
    if (h[threadIdx.x]) atomicAdd(&bktcnt[threadIdx.x], h[threadIdx.x]);
}

__global__ __launch_bounds__(256) void k_bktscan(const int* __restrict__ bktcnt,
                                                 int* __restrict__ bkt_base,
                                                 int* __restrict__ bkt_cursor,
                                                 int NB, int E) {
    __shared__ int sh[256];
    int t = threadIdx.x;
    int v = (t < NB) ? bktcnt[t] : 0;
    sh[t] = v;
    __syncthreads();
    for (int s = 1; s < 256; s <<= 1) {
        int u = (t >= s) ? sh[t - s] : 0;
        __syncthreads();
        sh[t] += u;
        __syncthreads();
    }
    int excl = sh[t] - v;
    if (t < NB) { bkt_base[t] = excl; bkt_cursor[t] = excl; }
    if (t == 0) bkt_base[NB] = E;
}

#define EPB 4096
__global__ __launch_bounds__(256) void k_binscatter(
        const int* __restrict__ src, const int* __restrict__ dst,
        int* __restrict__ bkt_cursor, uint2* __restrict__ ebuf, int E) {
    __shared__ int h[256];
    __shared__ int cb[256];
    int t = threadIdx.x;
    h[t] = 0;
    __syncthreads();
    int base = blockIdx.x * EPB;
    int es[16], ed[16], lp[16];
    #pragma unroll
    for (int it = 0; it < 16; ++it) {
        int i = base + it * 256 + t;
        if (i < E) {
            es[it] = src[i];
            ed[it] = dst[i];
            lp[it] = atomicAdd(&h[ed[it] >> 9], 1);
        } else {
            es[it] = -1; ed[it] = 0; lp[it] = 0;
        }
    }
    __syncthreads();
    int c = h[t];
    if (c) cb[t] = atomicAdd(&bkt_cursor[t], c);
    __syncthreads();
    #pragma unroll
    for (int it = 0; it < 16; ++it) {
        if (es[it] >= 0) {
            int b = ed[it] >> 9;
            ebuf[cb[b] + lp[it]] = make_uint2((unsigned)es[it], (unsigned)ed[it]);
        }
    }
}

// One block per bucket. Degrees -> padded scan (incl. SELF edge) -> rs/cnte/dinv,
// scatter edges, append self, pad-fill with dummy node Nn.
__global__ __launch_bounds__(256) void k_csrbuild(
        const uint2* __restrict__ ebuf, const int* __restrict__ bkt_base,
        int* __restrict__ rs, int* __restrict__ cnte, float* __restrict__ dinv,
        int* __restrict__ csr, int Nn) {
    __shared__ int deg[512];
    __shared__ int cur[512];
    __shared__ int ts[256];
    int b = blockIdx.x, t = threadIdx.x;
    int e0 = bkt_base[b], e1 = bkt_base[b + 1];
    int pb = e0 + b * BKT_SLACK;
    int node0 = b << 9;
    deg[t] = 0; deg[t + 256] = 0;
    __syncthreads();
    for (int j = e0 + t; j < e1; j += 256)
        atomicAdd(&deg[(int)ebuf[j].y - node0], 1);
    __syncthreads();
    int n0 = node0 + 2 * t;
    int d0 = deg[2 * t], d1 = deg[2 * t + 1];
    int p0 = (n0 < Nn)     ? ((d0 + 1 + PAD - 1) & ~(PAD - 1)) : 0;   // +1 self
    int p1 = (n0 + 1 < Nn) ? ((d1 + 1 + PAD - 1) & ~(PAD - 1)) : 0;
    ts[t] = p0 + p1;
    __syncthreads();
    for (int s = 1; s < 256; s <<= 1) {
        int u = (t >= s) ? ts[t - s] : 0;
        __syncthreads();
        ts[t] += u;
        __syncthreads();
    }
    int excl = ts[t] - (p0 + p1);
    cur[2 * t] = excl;
    cur[2 * t + 1] = excl + p0;
    if (n0 < Nn)     { rs[n0]     = pb + excl;      cnte[n0]     = p0; dinv[n0]     = rsqrtf((float)(d0 + 1)); }
    if (n0 + 1 < Nn) { rs[n0 + 1] = pb + excl + p0; cnte[n0 + 1] = p1; dinv[n0 + 1] = rsqrtf((float)(d1 + 1)); }
    __syncthreads();
    for (int j = e0 + t; j < e1; j += 256) {
        uint2 e = ebuf[j];
        int p = atomicAdd(&cur[(int)e.y - node0], 1);
        csr[pb + p] = (int)e.x;
    }
    if (n0 < Nn) {
        csr[pb + excl + d0] = n0;                                     // self
        for (int j = d0 + 1; j < p0; ++j) csr[pb + excl + j] = Nn;    // pad
    }
    if (n0 + 1 < Nn) {
        csr[pb + excl + p0 + d1] = n0 + 1;
        for (int j = d1 + 1; j < p1; ++j) csr[pb + excl + p0 + j] = Nn;
    }
}

// ---------------- Weight pack: (k,n) -> Wp[((k>>3)*Ncols + n)*8 + (k&7)] ----------------
__global__ void k_wpack(const float* __restrict__ W, unsigned short* __restrict__ Wp,
                        int K, int Ncols) {
    int i = blockIdx.x * blockDim.x + threadIdx.x;
    if (i < K * Ncols) {
        int k = i / Ncols, n = i - k * Ncols;
        Wp[((size_t)(k >> 3) * Ncols + n) * 8 + (k & 7)] = f2bf(W[i]);
    }
}

// ---------------- GEMM1 (MFMA bf16): hs1 = fp8((x @ W1 + b1) * dinv[row]) ----------------
__global__ __launch_bounds__(512) void k_gemm1(
        const float* __restrict__ x, const unsigned short* __restrict__ W1p,
        const float* __restrict__ b1, const float* __restrict__ dinv,
        unsigned char* __restrict__ hs1, int Nn) {
    __shared__ unsigned short As[64][40];
    int tid = threadIdx.x;
    int w = tid >> 6, lane = tid & 63;
    int wr = w >> 2, wc = w & 3;
    int l15 = lane & 15, l4 = lane >> 4;
    int row0 = blockIdx.x * 64;

    f32x4 zero = {0.f, 0.f, 0.f, 0.f};
    f32x4 acc[2][4];
    #pragma unroll
    for (int m = 0; m < 2; ++m)
        #pragma unroll
        for (int n = 0; n < 4; ++n) acc[m][n] = zero;

    int sr = tid >> 3;
    int sc = tid & 7;
    bool srok = (row0 + sr) < Nn;
    const float* xrow = x + (size_t)(row0 + sr) * FIN + sc * 4;

    for (int kt = 0; kt < FIN; kt += 32) {
        float4 v = srok ? *(const float4*)(xrow + kt) : make_float4(0.f, 0.f, 0.f, 0.f);
        ushort4 o;
        o.x = f2bf(v.x); o.y = f2bf(v.y); o.z = f2bf(v.z); o.w = f2bf(v.w);
        *(ushort4*)&As[sr][sc * 4] = o;
        __syncthreads();

        bf16x8 bfr[4];
        size_t bbase = (size_t)((kt >> 3) + l4) * HID * 8;
        #pragma unroll
        for (int n = 0; n < 4; ++n) {
            int col = wc * 64 + n * 16 + l15;
            bfr[n] = *(const bf16x8*)&W1p[bbase + (size_t)col * 8];
        }
        bf16x8 afr[2];
        #pragma unroll
        for (int m = 0; m < 2; ++m) {
            int r = wr * 32 + m * 16 + l15;
            afr[m] = *(const bf16x8*)&As[r][l4 * 8];
        }
        #pragma unroll
        for (int m = 0; m < 2; ++m)
            #pragma unroll
            for (int n = 0; n < 4; ++n)
                acc[m][n] = __builtin_amdgcn_mfma_f32_16x16x32_bf16(
                    afr[m], bfr[n], acc[m][n], 0, 0, 0);
        __syncthreads();
    }

    float b1c[4];
    #pragma unroll
    for (int n = 0; n < 4; ++n) b1c[n] = b1[wc * 64 + n * 16 + l15];
    #pragma unroll
    for (int m = 0; m < 2; ++m) {
        #pragma unroll
        for (int r = 0; r < 4; ++r) {
            int row = row0 + wr * 32 + m * 16 + l4 * 4 + r;
            if (row < Nn) {
                float dv = dinv[row];
                #pragma unroll
                for (int n = 0; n < 4; ++n) {
                    int col = wc * 64 + n * 16 + l15;
                    hs1[(size_t)row * HID + col] = f2fp8((acc[m][n][r] + b1c[n]) * dv);
                }
            }
        }
    }
}

// ---------------- Agg1: wave/dst, fp8 rows (256B), 16 lanes x 16B, 4 edges/instr ----------------
__global__ __launch_bounds__(256) void k_agg1(
        const unsigned char* __restrict__ hs1, const int* __restrict__ csr,
        const int* __restrict__ rs, const int* __restrict__ cnte,
        const float* __restrict__ dinv, unsigned short* __restrict__ h2in, int Nn) {
    int d = blockIdx.x * 4 + (threadIdx.x >> 6);
    if (d >= Nn) return;
    int lane = threadIdx.x & 63;
    int g = lane >> 4, c = lane & 15;
    size_t coff = (size_t)c * 16;
    float acc[16];
    #pragma unroll
    for (int j = 0; j < 16; ++j) acc[j] = 0.f;
    int base = rs[d], cnt = cnte[d];
    const int* cp = csr + base;
    int t = 0;
    for (; t + 16 <= cnt; t += 16) {
        int i0 = cp[t + g], i1 = cp[t + 4 + g], i2 = cp[t + 8 + g], i3 = cp[t + 12 + g];
        uint4 v0 = *(const uint4*)&hs1[(size_t)i0 * HID + coff];
        uint4 v1 = *(const uint4*)&hs1[(size_t)i1 * HID + coff];
        uint4 v2 = *(const uint4*)&hs1[(size_t)i2 * HID + coff];
        uint4 v3 = *(const uint4*)&hs1[(size_t)i3 * HID + coff];
        unsigned int w0[4] = {v0.x, v0.y, v0.z, v0.w};
        unsigned int w1[4] = {v1.x, v1.y, v1.z, v1.w};
        unsigned int w2[4] = {v2.x, v2.y, v2.z, v2.w};
        unsigned int w3[4] = {v3.x, v3.y, v3.z, v3.w};
        #pragma unroll
        for (int k = 0; k < 4; ++k) {
            f32x2 a0 = __builtin_amdgcn_cvt_pk_f32_fp8(w0[k], false);
            f32x2 b0 = __builtin_amdgcn_cvt_pk_f32_fp8(w0[k], true);
            f32x2 a1 = __builtin_amdgcn_cvt_pk_f32_fp8(w1[k], false);
            f32x2 b1v = __builtin_amdgcn_cvt_pk_f32_fp8(w1[k], true);
            f32x2 a2 = __builtin_amdgcn_cvt_pk_f32_fp8(w2[k], false);
            f32x2 b2v = __builtin_amdgcn_cvt_pk_f32_fp8(w2[k], true);
            f32x2 a3 = __builtin_amdgcn_cvt_pk_f32_fp8(w3[k], false);
            f32x2 b3 = __builtin_amdgcn_cvt_pk_f32_fp8(w3[k], true);
            acc[k*4+0] += (a0[0] + a1[0]) + (a2[0] + a3[0]);
            acc[k*4+1] += (a0[1] + a1[1]) + (a2[1] + a3[1]);
            acc[k*4+2] += (b0[0] + b1v[0]) + (b2v[0] + b3[0]);
            acc[k*4+3] += (b0[1] + b1v[1]) + (b2v[1] + b3[1]);
        }
    }
    if (t < cnt) {  // 8 remain
        int i0 = cp[t + g], i1 = cp[t + 4 + g];
        uint4 v0 = *(const uint4*)&hs1[(size_t)i0 * HID + coff];
        uint4 v1 = *(const uint4*)&hs1[(size_t)i1 * HID + coff];
        unsigned int w0[4] = {v0.x, v0.y, v0.z, v0.w};
        unsigned int w1[4] = {v1.x, v1.y, v1.z, v1.w};
        #pragma unroll
        for (int k = 0; k < 4; ++k) {
            f32x2 a0 = __builtin_amdgcn_cvt_pk_f32_fp8(w0[k], false);
            f32x2 b0 = __builtin_amdgcn_cvt_pk_f32_fp8(w0[k], true);
            f32x2 a1 = __builtin_amdgcn_cvt_pk_f32_fp8(w1[k], false);
            f32x2 b1v = __builtin_amdgcn_cvt_pk_f32_fp8(w1[k], true);
            acc[k*4+0] += a0[0] + a1[0];
            acc[k*4+1] += a0[1] + a1[1];
            acc[k*4+2] += b0[0] + b1v[0];
            acc[k*4+3] += b0[1] + b1v[1];
        }
    }
    #pragma unroll
    for (int j = 0; j < 16; ++j) {
        acc[j] += __shfl_xor(acc[j], 16);
        acc[j] += __shfl_xor(acc[j], 32);
    }
    float dv = dinv[d];
    ushort4 o;
    o.x = f2bf(fmaxf(acc[g * 4 + 0] * dv, 0.f));
    o.y = f2bf(fmaxf(acc[g * 4 + 1] * dv, 0.f));
    o.z = f2bf(fmaxf(acc[g * 4 + 2] * dv, 0.f));
    o.w = f2bf(fmaxf(acc[g * 4 + 3] * dv, 0.f));
    *(ushort4*)&h2in[(size_t)d * HID + c * 16 + g * 4] = o;
}

// ---------------- GEMM2 (MFMA): hs2 = (h2in @ W2 + b2) * dinv, no LDS ----------------
__global__ __launch_bounds__(256) void k_gemm2(
        const unsigned short* __restrict__ h2in, const unsigned short* __restrict__ W2p,
        const float* __restrict__ b2, const float* __restrict__ dinv,
        unsigned short* __restrict__ hs2, int Nn) {
    int tid = threadIdx.x;
    int w = tid >> 6, lane = tid & 63;
    int l15 = lane & 15, l4 = lane >> 4;
    int r0 = blockIdx.x * 64 + w * 16;
    int arow = r0 + l15;
    bool aok = arow < Nn;
    const unsigned short* ap = h2in + (size_t)arow * HID + l4 * 8;

    f32x4 zero = {0.f, 0.f, 0.f, 0.f};
    bf16x8 zf = {0, 0, 0, 0, 0, 0, 0, 0};
    f32x4 acc[4];
    #pragma unroll
    for (int n = 0; n < 4; ++n) acc[n] = zero;

    #pragma unroll
    for (int kt = 0; kt < HID; kt += 32) {
        bf16x8 a = aok ? *(const bf16x8*)(ap + kt) : zf;
        size_t bbase = (size_t)((kt >> 3) + l4) * CLS * 8;
        #pragma unroll
        for (int n = 0; n < 4; ++n) {
            bf16x8 bb = *(const bf16x8*)&W2p[bbase + (size_t)(n * 16 + l15) * 8];
            acc[n] = __builtin_amdgcn_mfma_f32_16x16x32_bf16(a, bb, acc[n], 0, 0, 0);
        }
    }
    float b2c[4];
    #pragma unroll
    for (int n = 0; n < 4; ++n) b2c[n] = b2[n * 16 + l15];
    #pragma unroll
    for (int r = 0; r < 4; ++r) {
        int row = r0 + l4 * 4 + r;
        if (row < Nn) {
            float dv = dinv[row];
            #pragma unroll
            for (int n = 0; n < 4; ++n)
                hs2[(size_t)row * CLS + n * 16 + l15] = f2bf((acc[n][r] + b2c[n]) * dv);
        }
    }
}

// ---------------- Agg2 + log_softmax: wave/dst, quarter-split, self via csr ----------------
__global__ __launch_bounds__(256) void k_agg2(
        const unsigned short* __restrict__ hs2, const int* __restrict__ csr,
        const int* __restrict__ rs, const int* __restrict__ cnte,
        const float* __restrict__ dinv, float* __restrict__ out, int Nn) {
    int d = blockIdx.x * 4 + (threadIdx.x >> 6);
    if (d >= Nn) return;
    int lane = threadIdx.x & 63;
    int q = lane >> 4, c4 = lane & 15;
    size_t loff = (size_t)c4 * 4;
    float a0 = 0.f, a1 = 0.f, a2 = 0.f, a3 = 0.f;
    int base = rs[d], cnt = cnte[d];
    const int* cp = csr + base;
    int t = 0;
    for (; t + 16 <= cnt; t += 16) {
        int s0 = cp[t + q], s1 = cp[t + q + 4], s2 = cp[t + q + 8], s3 = cp[t + q + 12];
        ushort4 v0 = *(const ushort4*)&hs2[(size_t)s0 * CLS + loff];
        ushort4 v1 = *(const ushort4*)&hs2[(size_t)s1 * CLS + loff];
        ushort4 v2 = *(const ushort4*)&hs2[(size_t)s2 * CLS + loff];
        ushort4 v3 = *(const ushort4*)&hs2[(size_t)s3 * CLS + loff];
        a0 += (bf2f(v0.x) + bf2f(v1.x)) + (bf2f(v2.x) + bf2f(v3.x));
        a1 += (bf2f(v0.y) + bf2f(v1.y)) + (bf2f(v2.y) + bf2f(v3.y));
        a2 += (bf2f(v0.z) + bf2f(v1.z)) + (bf2f(v2.z) + bf2f(v3.z));
        a3 += (bf2f(v0.w) + bf2f(v1.w)) + (bf2f(v2.w) + bf2f(v3.w));
    }
    if (t < cnt) {
        int s0 = cp[t + q], s1 = cp[t + q + 4];
        ushort4 v0 = *(const ushort4*)&hs2[(size_t)s0 * CLS + loff];
        ushort4 v1 = *(const ushort4*)&hs2[(size_t)s1 * CLS + loff];
        a0 += bf2f(v0.x) + bf2f(v1.x);
        a1 += bf2f(v0.y) + bf2f(v1.y);
        a2 += bf2f(v0.z) + bf2f(v1.z);
        a3 += bf2f(v0.w) + bf2f(v1.w);
    }
    a0 += __shfl_xor(a0, 16); a0 += __shfl_xor(a0, 32);
    a1 += __shfl_xor(a1, 16); a1 += __shfl_xor(a1, 32);
    a2 += __shfl_xor(a2, 16); a2 += __shfl_xor(a2, 32);
    a3 += __shfl_xor(a3, 16); a3 += __shfl_xor(a3, 32);
    float dv = dinv[d];
    float y0 = a0 * dv, y1 = a1 * dv, y2 = a2 * dv, y3 = a3 * dv;
    float m = fmaxf(fmaxf(y0, y1), fmaxf(y2, y3));
    #pragma unroll
    for (int o = 1; o <= 8; o <<= 1) m = fmaxf(m, __shfl_xor(m, o));
    float s = __expf(y0 - m) + __expf(y1 - m) + __expf(y2 - m) + __expf(y3 - m);
    #pragma unroll
    for (int o = 1; o <= 8; o <<= 1) s += __shfl_xor(s, o);
    if (q == 0) {
        float lg = __logf(s);
        float4 o4 = make_float4(y0 - m - lg, y1 - m - lg, y2 - m - lg, y3 - m - lg);
        *(float4*)&out[(size_t)d * CLS + c4 * 4] = o4;
    }
}

extern "C" void kernel_launch(void* const* d_in, const int* in_sizes, int n_in,
                              void* d_out, int out_size, void* d_ws, size_t ws_size,
                              hipStream_t stream) {
    const float* x  = (const float*)d_in[0];
    const int* ei   = (const int*)d_in[1];
    const float* W1 = (const float*)d_in[2];
    const float* b1 = (const float*)d_in[3];
    const float* W2 = (const float*)d_in[4];
    const float* b2 = (const float*)d_in[5];
    float* out = (float*)d_out;

    const int N = in_sizes[0] / FIN;
    const int E = in_sizes[1] / 2;
    const int NB = (N + 511) >> 9;
    const int* srcp = ei;
    const int* dstp = ei + E;

    char* w = (char*)d_ws;
    auto alloc = [&](size_t bytes) -> void* {
        void* p = (void*)w;
        w += (bytes + 255) / 256 * 256;
        return p;
    };
    int* rs        = (int*)alloc((size_t)(N + 1) * 4);
    int* cnte      = (int*)alloc((size_t)N * 4);
    float* dinv    = (float*)alloc((size_t)N * 4);
    int* csr       = (int*)alloc(((size_t)E + (size_t)N + (size_t)NB * BKT_SLACK + 8) * 4);
    int* bktcnt    = (int*)alloc((size_t)(NB + 1) * 4);
    int* bkt_base  = (int*)alloc((size_t)(NB + 1) * 4);
    int* bkt_cursor= (int*)alloc((size_t)(NB + 1) * 4);
    size_t hs1_bytes = (size_t)N * HID + HID;                 // fp8 rows + dummy row
    size_t ebuf_bytes = (size_t)E * 8;
    unsigned char* hs1 = (unsigned char*)alloc(hs1_bytes > ebuf_bytes ? hs1_bytes : ebuf_bytes + HID);
    unsigned short* h2in = (unsigned short*)alloc((size_t)N * HID * 2);
    unsigned short* hs2  = (unsigned short*)alloc((size_t)(N + 1) * CLS * 2);  // +1 dummy zero row
    unsigned short* W1p  = (unsigned short*)alloc((size_t)FIN * HID * 2);
    unsigned short* W2p  = (unsigned short*)alloc((size_t)HID * CLS * 2);
    // ebuf aliases hs1: dead after k_csrbuild, before k_gemm1 writes hs1 (stream-ordered).
    uint2* ebuf = (uint2*)hs1;

    hipMemsetAsync(bktcnt, 0, (size_t)(NB + 1) * 4, stream);

    k_hist<<<1024, 256, 0, stream>>>(dstp, bktcnt, E);
    k_bktscan<<<1, 256, 0, stream>>>(bktcnt, bkt_base, bkt_cursor, NB, E);
    k_binscatter<<<(E + EPB - 1) / EPB, 256, 0, stream>>>(srcp, dstp, bkt_cursor, ebuf, E);
    k_csrbuild<<<NB, 256, 0, stream>>>(ebuf, bkt_base, rs, cnte, dinv, csr, N);

    // dummy rows (index N) zeroed AFTER csrbuild (ebuf may overlap hs1's dummy row region)
    hipMemsetAsync(hs1 + (size_t)N * HID, 0, HID, stream);
    hipMemsetAsync(hs2 + (size_t)N * CLS, 0, CLS * 2, stream);

    k_wpack<<<(FIN * HID + 255) / 256, 256, 0, stream>>>(W1, W1p, FIN, HID);
    k_wpack<<<(HID * CLS + 255) / 256, 256, 0, stream>>>(W2, W2p, HID, CLS);

    k_gemm1<<<(N + 63) / 64, 512, 0, stream>>>(x, W1p, b1, dinv, hs1, N);
    k_agg1<<<(N + 3) / 4, 256, 0, stream>>>(hs1, csr, rs, cnte, dinv, h2in, N);
    k_gemm2<<<(N + 63) / 64, 256, 0, stream>>>(h2in, W2p, b2, dinv, hs2, N);
    k_agg2<<<(N + 3) / 4, 256, 0, stream>>>(hs2, csr, rs, cnte, dinv, out, N);
}